// Round 3
// baseline (703.300 us; speedup 1.0000x reference)
//
#include <hip/hip_runtime.h>

// Linear-attention decode step, slot-deduplicated.
// out[b,h,e] = valid(b) ? (q·k)[b,h]*v[b,h,e] + exp(-slope[h]) * sum_d q[b,h,d]*KV[slot[b],h,d,e] : 0
// B=128 H=64 D=96 S=256, all fp32.
//
// R2: bin b's by slot (E[unique slots] ~ 101 of 128), then one block per
// (slot,h) streams the 36 KB tile ONCE and applies every q that maps to it.
// Tile HBM traffic: 302 MB -> unique_slots * 2.36 MB (~240 MB expected).

#define NB 128
#define NH 64
#define ND 96
#define NS 256
#define CH 4   // b's processed per tile stream (c>CH loops; P(c>4) tiny)

// ws layout: int cnt[NS+1]; int lists[(NS+1)*NB]
// bucket NS = invalid (slot<0) b's -> zero output.

__global__ __launch_bounds__(256) void bin_slots(const int* __restrict__ slot_idx,
                                                 int* __restrict__ cnt,
                                                 int* __restrict__ lists) {
    __shared__ int lc[NS + 1];
    const int t = threadIdx.x;
    for (int i = t; i < NS + 1; i += 256) lc[i] = 0;
    __syncthreads();
    if (t < NB) {
        const int s = slot_idx[t];
        const int idx = (s >= 0 && s < NS) ? s : NS;
        const int p = atomicAdd(&lc[idx], 1);
        lists[idx * NB + p] = t;
    }
    __syncthreads();
    for (int i = t; i < NS + 1; i += 256) cnt[i] = lc[i];
}

__global__ __launch_bounds__(128, 4) void la_decode(
    const float* __restrict__ q, const float* __restrict__ k,
    const float* __restrict__ v, const float* __restrict__ kvc,
    const float* __restrict__ slope, const int* __restrict__ cnt,
    const int* __restrict__ lists, float* __restrict__ out)
{
    const int s = blockIdx.x;      // 0..NS  (NS = invalid bucket)
    const int h = blockIdx.y;
    const int t = threadIdx.x;

    const int c = cnt[s];
    if (c == 0) return;

    if (s == NS) {                 // invalid b's: out = 0
        for (int i = 0; i < c; ++i) {
            const int b = lists[NS * NB + i];
            if (t < ND) out[((size_t)b * NH + h) * ND + t] = 0.f;
        }
        return;
    }

    __shared__ float qt[ND][CH];       // transposed q: qt[d][bi], 16 B rows for ds_read_b128
    __shared__ float ks[CH][100];      // k staging (padded rows, conflict-free column dots)
    __shared__ float qk[CH];
    __shared__ float part[4][CH][ND];  // dp-partition partials per bi

    const float ratio = __expf(-slope[h]);
    const float* __restrict__ tile = kvc + ((size_t)s * NH + h) * (size_t)(ND * ND);

    const int dp = t / 24;             // 0..3 (t<96)
    const int e4 = t % 24;             // 0..23

    for (int cb = 0; cb < c; cb += CH) {
        const int cc = min(CH, c - cb);
        __syncthreads();               // protect qt/ks/part reuse across chunks

        // Stage q (transposed) and k; zero-pad bi >= cc.
        if (t < ND) {
            #pragma unroll
            for (int bi = 0; bi < CH; ++bi) {
                if (bi < cc) {
                    const int b = lists[s * NB + cb + bi];
                    const size_t off = ((size_t)b * NH + h) * ND + t;
                    qt[t][bi] = q[off];
                    ks[bi][t] = k[off];
                } else {
                    qt[t][bi] = 0.f;
                    ks[bi][t] = 0.f;
                }
            }
        }
        __syncthreads();

        // qk[bi] = q·k (4 threads, serial dots from LDS; banks distinct).
        if (t < CH) {
            float d = 0.f;
            for (int i = 0; i < ND; ++i) d += qt[i][t] * ks[t][i];
            qk[t] = d;
        }
        __syncthreads();

        // Stream the 36 KB tile once; float4-contiguous (addr = base + j*1536 + 16t).
        float4 acc[CH];
        #pragma unroll
        for (int bi = 0; bi < CH; ++bi) acc[bi] = make_float4(0.f, 0.f, 0.f, 0.f);

        if (t < 96) {
            const float4* __restrict__ tp4 = (const float4*)(tile + 4 * t);
            #pragma unroll 8
            for (int j = 0; j < 24; ++j) {
                const float4 kv4 = tp4[j * 96];                 // d = 4j+dp, cols e4*4..+3
                const float4 qd = *(const float4*)&qt[4 * j + dp][0];  // q[d][bi=0..3]
                acc[0].x = fmaf(qd.x, kv4.x, acc[0].x);
                acc[0].y = fmaf(qd.x, kv4.y, acc[0].y);
                acc[0].z = fmaf(qd.x, kv4.z, acc[0].z);
                acc[0].w = fmaf(qd.x, kv4.w, acc[0].w);
                acc[1].x = fmaf(qd.y, kv4.x, acc[1].x);
                acc[1].y = fmaf(qd.y, kv4.y, acc[1].y);
                acc[1].z = fmaf(qd.y, kv4.z, acc[1].z);
                acc[1].w = fmaf(qd.y, kv4.w, acc[1].w);
                acc[2].x = fmaf(qd.z, kv4.x, acc[2].x);
                acc[2].y = fmaf(qd.z, kv4.y, acc[2].y);
                acc[2].z = fmaf(qd.z, kv4.z, acc[2].z);
                acc[2].w = fmaf(qd.z, kv4.w, acc[2].w);
                acc[3].x = fmaf(qd.w, kv4.x, acc[3].x);
                acc[3].y = fmaf(qd.w, kv4.y, acc[3].y);
                acc[3].z = fmaf(qd.w, kv4.z, acc[3].z);
                acc[3].w = fmaf(qd.w, kv4.w, acc[3].w);
            }
            #pragma unroll
            for (int bi = 0; bi < CH; ++bi)
                *(float4*)&part[dp][bi][e4 * 4] = acc[bi];
        }
        __syncthreads();

        // Epilogue: fold 4 dp-partitions, add (q·k)*v, scale, store.
        if (t < ND) {
            for (int bi = 0; bi < cc; ++bi) {
                const int b = lists[s * NB + cb + bi];
                const float dot = part[0][bi][t] + part[1][bi][t]
                                + part[2][bi][t] + part[3][bi][t];
                const size_t off = ((size_t)b * NH + h) * ND + t;
                out[off] = fmaf(qk[bi], v[off], ratio * dot);
            }
        }
    }
}

extern "C" void kernel_launch(void* const* d_in, const int* in_sizes, int n_in,
                              void* d_out, int out_size, void* d_ws, size_t ws_size,
                              hipStream_t stream) {
    const float* q     = (const float*)d_in[0];
    const float* k     = (const float*)d_in[1];
    const float* v     = (const float*)d_in[2];
    const float* kvc   = (const float*)d_in[3];
    const float* slope = (const float*)d_in[4];
    const int*   slot  = (const int*)d_in[5];
    float* out = (float*)d_out;

    int* cnt   = (int*)d_ws;
    int* lists = cnt + (NS + 1);

    bin_slots<<<1, 256, 0, stream>>>(slot, cnt, lists);

    dim3 grid(NS + 1, NH);
    la_decode<<<grid, dim3(128), 0, stream>>>(q, k, v, kvc, slope, cnt, lists, out);
}